// Round 1
// baseline (156.389 us; speedup 1.0000x reference)
//
#include <hip/hip_runtime.h>
#include <cstdint>
#include <cstddef>

// ManualChebConv: out[b,n,fo] = sum_k Zk[b] @ W[k] + bias
//   Z0 = x, Z1 = L@x, Zk = 2*L@Z_{k-1} - Z_{k-2}, K=5
// B=1024, N=512, F_in=16, F_out=8. L symmetric 512x512 fp32.
//
// Design: 1 block per 4 batches (256 blocks = 1/CU, 512 thr = 8 waves).
// Z kept in LDS as bf16, transposed Z^T[col=4*16][n=512], stride 520 (+8 pad
// -> ds_read_b128 B-fragments hit banks 2-way = free). Two ping-pong buffers,
// recurrence overwrites prev in place (same lane reads-then-writes the same
// element -> race-free). L converted once to bf16 in d_ws, streamed as MFMA
// A-fragments (16B/lane global loads, L2-resident 512KB). kstep-outer K-loop
// so each B-fragment feeds 4 M-tiles (else LDS-bound). Epilogue sum Zk@Wk via
// paired 16x16x32 MFMAs ((Z0,Z1)(W0;W1), (Z2,Z3)(W2;W3), (Z4,0)(W4;0)).

typedef __attribute__((ext_vector_type(8))) short  frag_ab;  // 8 bf16
typedef __attribute__((ext_vector_type(4))) float  frag_cd;  // 4 fp32

constexpr int BN    = 512;        // N
constexpr int FIN   = 16;
constexpr int FOUT  = 8;
constexpr int BT    = 4;          // batches per block
constexpr int NCOLS = BT * FIN;   // 64 combined cols
constexpr int LDST  = BN + 8;     // 520 bf16: padded stride (bank-friendly, 16B aligned)
constexpr int ZBUF  = NCOLS * LDST;  // 33280 elements per buffer

__device__ __forceinline__ uint16_t f2bf(float f) {
    uint32_t u = __builtin_bit_cast(uint32_t, f);
    u += 0x7FFFu + ((u >> 16) & 1u);          // round-to-nearest-even
    return (uint16_t)(u >> 16);
}
__device__ __forceinline__ float bf2f(uint16_t h) {
    uint32_t u = ((uint32_t)h) << 16;
    return __builtin_bit_cast(float, u);
}

__global__ void cvtL(const float* __restrict__ Lf, uint16_t* __restrict__ Lb) {
    int i = blockIdx.x * 256 + threadIdx.x;   // 1024 blocks x 256 = 262144
    Lb[i] = f2bf(Lf[i]);
}

template <bool LBF16>
__global__ __launch_bounds__(512, 2)
void cheb_kernel(const float* __restrict__ x, const float* __restrict__ Lf,
                 const uint16_t* __restrict__ Lb, const float* __restrict__ W,
                 const float* __restrict__ bvec, float* __restrict__ out) {
    __shared__ uint16_t lds[2 * ZBUF];        // 133,120 B of the 160 KB LDS
    uint16_t* z0 = lds;
    uint16_t* z1 = lds + ZBUF;

    const int tid  = threadIdx.x;
    const int wave = tid >> 6;                // 0..7
    const int lane = tid & 63;
    const int lr   = lane & 15;               // A-row / B-col / D-col within tile
    const int q    = lane >> 4;               // quad: k-chunk for A/B, row-chunk for D

    // ---------------- stage x -> Z0^T (bf16) in z0 ----------------
    // Each assignment: (bl, f-chunk of 4, n-octet) -> read 8 float4 (rows n..n+7,
    // cols f0..f0+3), transpose in regs, 4x ds_write_b128 (8 consecutive n per col).
    const float4* x4 = reinterpret_cast<const float4*>(x + (size_t)blockIdx.x * (BT * BN * FIN));
    for (int s = 0; s < 2; ++s) {
        int a   = tid + s * 512;              // 1024 assignments
        int f0g = a & 3;
        int n8  = (a >> 2) & 63;
        int bl  = a >> 8;
        int jb  = bl * 2048 + n8 * 32 + f0g;  // float4 index of (bl, n8*8, f-chunk)
        float4 v[8];
#pragma unroll
        for (int r = 0; r < 8; ++r) v[r] = x4[jb + r * 4];
        int cb = bl * 16 + f0g * 4;
        int nb = n8 * 8;
#pragma unroll
        for (int w = 0; w < 4; ++w) {
            frag_ab pk;
#pragma unroll
            for (int r = 0; r < 8; ++r)
                pk[r] = (short)f2bf(reinterpret_cast<const float*>(&v[r])[w]);
            *reinterpret_cast<frag_ab*>(&z0[(cb + w) * LDST + nb]) = pk;
        }
    }

    // ---------------- W pair B-fragments + bias (in regs, once) ----------------
    // pair p: B[k][fo], k<16 -> W[2p][k][:], k>=16 -> W[2p+1][k-16][:]; zero pad
    // for fo>=8 and for the missing W5 half of pair 2.
    frag_ab wf[3];
#pragma unroll
    for (int p = 0; p < 3; ++p) {
        frag_ab t;
#pragma unroll
        for (int jj = 0; jj < 8; ++jj) {
            int k   = q * 8 + jj;
            int ki  = p * 2 + (k >> 4);
            int fin = k & 15;
            float val = (lr < 8 && ki < 5) ? W[ki * (FIN * FOUT) + fin * FOUT + lr] : 0.0f;
            t[jj] = (short)f2bf(val);
        }
        wf[p] = t;
    }
    const float bv = (lr < 8) ? bvec[lr] : 0.0f;

    frag_cd accOut[4][4] = {};                // [mtIdx][bt] out tiles (fp32)

    // A-fragment: L[row = mt*16+lr][ kb = ks*32 + q*8 .. +8 ]
    auto loadA = [&](int mt, int ks) -> frag_ab {
        int row = mt * 16 + lr;
        int kb  = ks * 32 + q * 8;
        if constexpr (LBF16) {
            return *reinterpret_cast<const frag_ab*>(Lb + row * BN + kb);
        } else {
            const float4* p  = reinterpret_cast<const float4*>(Lf + row * BN + kb);
            float4 u0 = p[0], u1 = p[1];
            frag_ab t;
            t[0] = (short)f2bf(u0.x); t[1] = (short)f2bf(u0.y);
            t[2] = (short)f2bf(u0.z); t[3] = (short)f2bf(u0.w);
            t[4] = (short)f2bf(u1.x); t[5] = (short)f2bf(u1.y);
            t[6] = (short)f2bf(u1.z); t[7] = (short)f2bf(u1.w);
            return t;
        }
    };

    // One application: dst = L@cur (first) or 2*L@cur - dst (in-place recurrence).
    auto app = [&](const uint16_t* cur, uint16_t* dst, bool first) {
        frag_cd acc[4][4] = {};               // [mtIdx][ct]
        for (int ks = 0; ks < 16; ++ks) {
            frag_ab bfr[4];
#pragma unroll
            for (int ct = 0; ct < 4; ++ct)    // B-frag reused by 4 M-tiles
                bfr[ct] = *reinterpret_cast<const frag_ab*>(
                    cur + (ct * 16 + lr) * LDST + ks * 32 + q * 8);
#pragma unroll
            for (int mi = 0; mi < 4; ++mi) {
                frag_ab a = loadA(wave + mi * 8, ks);
#pragma unroll
                for (int ct = 0; ct < 4; ++ct)
                    acc[mi][ct] = __builtin_amdgcn_mfma_f32_16x16x32_bf16(
                        a, bfr[ct], acc[mi][ct], 0, 0, 0);
            }
        }
        // writeback: D lane holds rows q*4+r, col lr (per tile)
#pragma unroll
        for (int mi = 0; mi < 4; ++mi) {
            int row0 = (wave + mi * 8) * 16 + q * 4;
#pragma unroll
            for (int ct = 0; ct < 4; ++ct) {
                uint16_t* dp = dst + (ct * 16 + lr) * LDST + row0;
                float pz[4] = {0.f, 0.f, 0.f, 0.f};
                if (!first) {
                    ushort4 pv = *reinterpret_cast<const ushort4*>(dp);
                    pz[0] = bf2f(pv.x); pz[1] = bf2f(pv.y);
                    pz[2] = bf2f(pv.z); pz[3] = bf2f(pv.w);
                }
                ushort4 nv;
                float v0 = acc[mi][ct][0], v1 = acc[mi][ct][1];
                float v2 = acc[mi][ct][2], v3 = acc[mi][ct][3];
                if (!first) {
                    v0 = 2.f * v0 - pz[0]; v1 = 2.f * v1 - pz[1];
                    v2 = 2.f * v2 - pz[2]; v3 = 2.f * v3 - pz[3];
                }
                nv.x = f2bf(v0); nv.y = f2bf(v1); nv.z = f2bf(v2); nv.w = f2bf(v3);
                *reinterpret_cast<ushort4*>(dp) = nv;
            }
        }
    };

    // Paired epilogue: accOut += [bufA | bufB](A-layout) @ wfr
    auto epi = [&](const uint16_t* bA, const uint16_t* bB, frag_ab wfr) {
        const uint16_t* base = (q < 2) ? bA : bB;
        int finb = (q & 1) * 8;
#pragma unroll
        for (int mi = 0; mi < 4; ++mi) {
            int n = (wave + mi * 8) * 16 + lr;
#pragma unroll
            for (int bt = 0; bt < 4; ++bt) {
                const uint16_t* pp = base + (bt * 16 + finb) * LDST + n;
                frag_ab afr;
#pragma unroll
                for (int jj = 0; jj < 8; ++jj) afr[jj] = (short)pp[jj * LDST];
                accOut[mi][bt] = __builtin_amdgcn_mfma_f32_16x16x32_bf16(
                    afr, wfr, accOut[mi][bt], 0, 0, 0);
            }
        }
    };

    __syncthreads();
    app(z0, z1, true);        // Z1 -> z1
    __syncthreads();
    epi(z0, z1, wf[0]);       // out += Z0@W0 + Z1@W1
    __syncthreads();
    app(z1, z0, false);       // Z2 -> z0 (over Z0)
    __syncthreads();
    app(z0, z1, false);       // Z3 -> z1 (over Z1)
    __syncthreads();
    epi(z0, z1, wf[1]);       // out += Z2@W2 + Z3@W3
    __syncthreads();
    app(z1, z0, false);       // Z4 -> z0 (over Z2)
    __syncthreads();
    epi(z0, z0, wf[2]);       // out += Z4@W4 (second half weights are zero)

    // ---------------- store ----------------
    if (lr < 8) {
        float* ob = out + (size_t)blockIdx.x * BT * BN * FOUT;
#pragma unroll
        for (int mi = 0; mi < 4; ++mi) {
            int row0 = (wave + mi * 8) * 16 + q * 4;
#pragma unroll
            for (int bt = 0; bt < 4; ++bt) {
                float* op = ob + bt * (BN * FOUT) + row0 * FOUT + lr;
                op[0 * FOUT] = accOut[mi][bt][0] + bv;
                op[1 * FOUT] = accOut[mi][bt][1] + bv;
                op[2 * FOUT] = accOut[mi][bt][2] + bv;
                op[3 * FOUT] = accOut[mi][bt][3] + bv;
            }
        }
    }
}

extern "C" void kernel_launch(void* const* d_in, const int* in_sizes, int n_in,
                              void* d_out, int out_size, void* d_ws, size_t ws_size,
                              hipStream_t stream) {
    const float* x  = (const float*)d_in[0];   // [1024,512,16]
    const float* Lf = (const float*)d_in[1];   // [512,512]
    const float* W  = (const float*)d_in[2];   // [5,16,8]
    const float* bv = (const float*)d_in[3];   // [8]
    float* out = (float*)d_out;                // [1024,512,8]

    if (ws_size >= (size_t)(BN * BN * sizeof(uint16_t))) {
        uint16_t* Lb = (uint16_t*)d_ws;
        cvtL<<<dim3(1024), dim3(256), 0, stream>>>(Lf, Lb);
        cheb_kernel<true><<<dim3(256), dim3(512), 0, stream>>>(x, Lf, Lb, W, bv, out);
    } else {
        // ws too small for bf16 L: convert L in-register per A-load (2x L2 traffic)
        cheb_kernel<false><<<dim3(256), dim3(512), 0, stream>>>(x, Lf, nullptr, W, bv, out);
    }
}